// Round 1
// baseline (436.042 us; speedup 1.0000x reference)
//
#include <hip/hip_runtime.h>
#include <math.h>

#define SEQ 128
#define DM 256
#define NHEAD 8
#define HDIM 32
#define NQKV 768
#define LN_EPS 1e-5f
#define ATT_SCALE 0.17677669529663687f  // 32^-0.5

__device__ const float INVF[8] = {
    1.0f, 0.31622776601683794f, 0.1f, 0.031622776601683794f,
    0.01f, 0.0031622776601683794f, 0.001f, 0.00031622776601683794f};

// ---------------- LayerNorm: one row (256 elems) per block ----------------
__global__ __launch_bounds__(256)
void ln_kernel(const float* __restrict__ pa, const float* __restrict__ gamma,
               const float* __restrict__ beta, float* __restrict__ xln) {
    int row = blockIdx.x;
    int tid = threadIdx.x;
    const float* rp = pa + (size_t)row * DM;
    float v = rp[tid];

    __shared__ float red[4];
    __shared__ float red2[4];
    int lane = tid & 63, wid = tid >> 6;

    float s = v;
    #pragma unroll
    for (int o = 32; o > 0; o >>= 1) s += __shfl_down(s, o);
    if (lane == 0) red[wid] = s;
    __syncthreads();
    float mean = (red[0] + red[1] + red[2] + red[3]) * (1.0f / DM);

    float d = v - mean;
    float sq = d * d;
    #pragma unroll
    for (int o = 32; o > 0; o >>= 1) sq += __shfl_down(sq, o);
    if (lane == 0) red2[wid] = sq;
    __syncthreads();
    float var = (red2[0] + red2[1] + red2[2] + red2[3]) * (1.0f / DM);

    float xn = d * rsqrtf(var + LN_EPS);
    xln[(size_t)row * DM + tid] = xn * gamma[tid] + beta[tid];
}

// ---------------- GEMM C[M,N] = A[M,K=256] * B[N,K]^T, optional rotary ----
// BM=BN=64, BK=16, 256 threads, 4x4 micro-tile.
template <bool ROTARY>
__global__ __launch_bounds__(256)
void gemm_nt(const float* __restrict__ A, int lda,
             const float* __restrict__ B,  // N x 256 row-major
             float* __restrict__ C, int ldc) {
    const int K = 256, BK = 16;
    __shared__ __align__(16) float As[BK][64 + 4];
    __shared__ __align__(16) float Bs[BK][64 + 4];

    int m0 = blockIdx.x * 64;
    int n0 = blockIdx.y * 64;
    int tid = threadIdx.x;
    int tx = tid & 15, ty = tid >> 4;
    int lRow = tid >> 2;         // 0..63
    int lK = (tid & 3) * 4;      // 0,4,8,12

    float acc[4][4] = {};

    for (int k0 = 0; k0 < K; k0 += BK) {
        float4 a = *(const float4*)(A + (size_t)(m0 + lRow) * lda + k0 + lK);
        float4 b = *(const float4*)(B + (size_t)(n0 + lRow) * K + k0 + lK);
        As[lK + 0][lRow] = a.x; As[lK + 1][lRow] = a.y;
        As[lK + 2][lRow] = a.z; As[lK + 3][lRow] = a.w;
        Bs[lK + 0][lRow] = b.x; Bs[lK + 1][lRow] = b.y;
        Bs[lK + 2][lRow] = b.z; Bs[lK + 3][lRow] = b.w;
        __syncthreads();
        #pragma unroll
        for (int kk = 0; kk < BK; ++kk) {
            float4 av = *(const float4*)&As[kk][ty * 4];
            float4 bv = *(const float4*)&Bs[kk][tx * 4];
            float aa[4] = {av.x, av.y, av.z, av.w};
            float bb[4] = {bv.x, bv.y, bv.z, bv.w};
            #pragma unroll
            for (int i = 0; i < 4; ++i)
                #pragma unroll
                for (int j = 0; j < 4; ++j) acc[i][j] += aa[i] * bb[j];
        }
        __syncthreads();
    }

    if (ROTARY) {
        int nq = n0 + tx * 4;
        bool need = (nq < 32) || (nq >= 256 && nq < 288);
        if (need) {
            int c = nq & 31;  // 0..28, multiple of 4
            #pragma unroll
            for (int i = 0; i < 4; ++i) {
                int r = m0 + ty * 4 + i;
                int yy = r & 127, xx = (r >> 7) & 127;
                float tX = -1.0f + (2.0f / 127.0f) * (float)xx;
                float tY = -1.0f + (2.0f / 127.0f) * (float)yy;
                #pragma unroll
                for (int p = 0; p < 2; ++p) {
                    int pi = (c >> 1) + p;
                    float th = ((pi < 8) ? tX : tY) * INVF[pi & 7];
                    float cs = cosf(th), sn = sinf(th);
                    float v0 = acc[i][2 * p], v1 = acc[i][2 * p + 1];
                    acc[i][2 * p]     = v0 * cs - v1 * sn;
                    acc[i][2 * p + 1] = v1 * cs + v0 * sn;
                }
            }
        }
    }

    #pragma unroll
    for (int i = 0; i < 4; ++i) {
        int m = m0 + ty * 4 + i;
        float4 o = {acc[i][0], acc[i][1], acc[i][2], acc[i][3]};
        *(float4*)(C + (size_t)m * ldc + n0 + tx * 4) = o;
    }
}

// ---------------- Attention: one (b,x,h) per block, 128 threads -----------
// Reads q/k/v from qkv buffer; writes output IN PLACE over the q slice
// (disjoint columns per head -> no cross-block race).
__global__ __launch_bounds__(128)
void attn_kernel(float* __restrict__ qkv, const int* __restrict__ mask) {
    __shared__ __align__(16) float Ks[SEQ * HDIM];
    __shared__ __align__(16) float Vs[SEQ * HDIM];
    __shared__ float Msel[SEQ];

    int blk = blockIdx.x;
    int h = blk & 7, bx = blk >> 3;
    float* base = qkv + (size_t)bx * SEQ * NQKV;
    int kb = 256 + h * HDIM, vb = 512 + h * HDIM;
    int tid = threadIdx.x;

    #pragma unroll
    for (int u = 0; u < 8; ++u) {
        int flat = u * 512 + tid * 4;
        int row = flat >> 5, col = flat & 31;
        *(float4*)&Ks[flat] = *(const float4*)(base + row * NQKV + kb + col);
        *(float4*)&Vs[flat] = *(const float4*)(base + row * NQKV + vb + col);
    }
    if (tid < SEQ) Msel[tid] = mask[bx * SEQ + tid] ? 0.0f : 1.0f;

    float q[HDIM];
    const float* qp = base + tid * NQKV + h * HDIM;
    #pragma unroll
    for (int u = 0; u < 8; ++u) {
        float4 t = *(const float4*)(qp + u * 4);
        q[4 * u + 0] = t.x; q[4 * u + 1] = t.y;
        q[4 * u + 2] = t.z; q[4 * u + 3] = t.w;
    }
    __syncthreads();

    float acc[HDIM] = {};
    float sumE = 0.0f;
    for (int j = 0; j < SEQ; ++j) {
        float s = 0.0f;
        #pragma unroll
        for (int d = 0; d < HDIM; ++d) s += q[d] * Ks[j * HDIM + d];
        float e = __expf(s * ATT_SCALE) * Msel[j];
        sumE += e;
        #pragma unroll
        for (int d = 0; d < HDIM; ++d) acc[d] += e * Vs[j * HDIM + d];
    }
    float inv = 1.0f / sumE;
    float* op = base + tid * NQKV + h * HDIM;
    #pragma unroll
    for (int u = 0; u < 8; ++u) {
        float4 o = {acc[4 * u + 0] * inv, acc[4 * u + 1] * inv,
                    acc[4 * u + 2] * inv, acc[4 * u + 3] * inv};
        *(float4*)(op + u * 4) = o;
    }
}

extern "C" void kernel_launch(void* const* d_in, const int* in_sizes, int n_in,
                              void* d_out, int out_size, void* d_ws, size_t ws_size,
                              hipStream_t stream) {
    const float* pair_act = (const float*)d_in[0];
    const int*   pair_mask = (const int*)d_in[1];
    const float* ln_gamma = (const float*)d_in[2];
    const float* ln_beta  = (const float*)d_in[3];
    const float* Wqkv = (const float*)d_in[4];
    const float* Wout = (const float*)d_in[5];
    float* out = (float*)d_out;

    const int B = 2;
    const int R = B * SEQ * SEQ;  // 32768 rows

    float* qkv = (float*)d_ws;          // R x 768
    float* xln = out;                   // reuse d_out as x_ln scratch

    // 1) LayerNorm -> xln (in d_out)
    ln_kernel<<<R, 256, 0, stream>>>(pair_act, ln_gamma, ln_beta, xln);

    // 2) QKV GEMM + rotary epilogue: qkv[R,768] = xln[R,256] @ Wqkv^T
    gemm_nt<true><<<dim3(R / 64, NQKV / 64), 256, 0, stream>>>(
        xln, DM, Wqkv, qkv, NQKV);

    // 3) Attention per (b,x,h); output overwrites q slice of qkv
    attn_kernel<<<B * SEQ * NHEAD, 128, 0, stream>>>(qkv, pair_mask);

    // 4) Output GEMM: out[R,256] = attn_out[R,256 (lda=768)] @ Wout^T
    gemm_nt<false><<<dim3(R / 64, DM / 64), 256, 0, stream>>>(
        qkv, NQKV, Wout, out, DM);
}

// Round 2
// 179.229 us; speedup vs baseline: 2.4329x; 2.4329x over previous
//
#include <hip/hip_runtime.h>
#include <math.h>

typedef __attribute__((ext_vector_type(8))) short short8;
typedef __attribute__((ext_vector_type(4))) float floatx4;

#define SEQ 128
#define DM 256
#define NQKV 768
#define LN_EPS 1e-5f
#define ATT_SCALE 0.17677669529663687f  // 32^-0.5

__device__ __constant__ float INVF[8] = {
    1.0f, 0.31622776601683794f, 0.1f, 0.031622776601683794f,
    0.01f, 0.0031622776601683794f, 0.001f, 0.00031622776601683794f};

__device__ inline unsigned short f2bf(float f) {
    unsigned u = __float_as_uint(f);
    u += 0x7fffu + ((u >> 16) & 1u);
    return (unsigned short)(u >> 16);
}
__device__ inline float bf2f(unsigned short s) {
    return __uint_as_float(((unsigned)s) << 16);
}

// ---------------- LayerNorm -> bf16 ----------------
__global__ __launch_bounds__(256)
void ln_kernel(const float* __restrict__ pa, const float* __restrict__ gamma,
               const float* __restrict__ beta, unsigned short* __restrict__ xln) {
    int row = blockIdx.x;
    int tid = threadIdx.x;
    float v = pa[(size_t)row * DM + tid];

    __shared__ float red[4];
    __shared__ float red2[4];
    int lane = tid & 63, wid = tid >> 6;

    float s = v;
    #pragma unroll
    for (int o = 32; o > 0; o >>= 1) s += __shfl_down(s, o);
    if (lane == 0) red[wid] = s;
    __syncthreads();
    float mean = (red[0] + red[1] + red[2] + red[3]) * (1.0f / DM);

    float d = v - mean;
    float sq = d * d;
    #pragma unroll
    for (int o = 32; o > 0; o >>= 1) sq += __shfl_down(sq, o);
    if (lane == 0) red2[wid] = sq;
    __syncthreads();
    float var = (red2[0] + red2[1] + red2[2] + red2[3]) * (1.0f / DM);

    float xn = d * rsqrtf(var + LN_EPS);
    xln[(size_t)row * DM + tid] = f2bf(xn * gamma[tid] + beta[tid]);
}

// ---------------- weights fp32 -> bf16 ----------------
__global__ __launch_bounds__(256)
void convw(const float* __restrict__ wq, const float* __restrict__ wo,
           unsigned short* __restrict__ bq, unsigned short* __restrict__ bo) {
    int i = blockIdx.x * 256 + threadIdx.x;
    if (i < NQKV * DM) bq[i] = f2bf(wq[i]);
    if (i < DM * DM) bo[i] = f2bf(wo[i]);
}

// ---------------- MFMA GEMM: C[M,N] = A[M,256] * B[N,256]^T ----------------
// 128x128 tile, BK=64, 4 waves each 64x64.
template <bool OUTBF16>
__global__ __launch_bounds__(256)
void gemm_mfma(const unsigned short* __restrict__ A,
               const unsigned short* __restrict__ B,
               void* __restrict__ Cout, int N) {
    __shared__ __align__(16) unsigned short As[128 * 72];
    __shared__ __align__(16) unsigned short Bs[128 * 72];
    int m0 = blockIdx.x * 128, n0 = blockIdx.y * 128;
    int tid = threadIdx.x;
    int wave = tid >> 6, lane = tid & 63, qd = lane >> 4, lo = lane & 15;
    int wm = (wave & 1) * 64, wn = (wave >> 1) * 64;

    floatx4 acc[4][4];
    #pragma unroll
    for (int i = 0; i < 4; ++i)
        #pragma unroll
        for (int j = 0; j < 4; ++j) acc[i][j] = (floatx4){0.f, 0.f, 0.f, 0.f};

    int srow = tid >> 1, shalf = tid & 1;
    const unsigned short* ap = A + (size_t)(m0 + srow) * 256 + shalf * 32;
    const unsigned short* bp = B + (size_t)(n0 + srow) * 256 + shalf * 32;
    unsigned short* asd = &As[srow * 72 + shalf * 32];
    unsigned short* bsd = &Bs[srow * 72 + shalf * 32];

    for (int k0 = 0; k0 < 256; k0 += 64) {
        short8 a0 = *(const short8*)(ap + k0);
        short8 a1 = *(const short8*)(ap + k0 + 8);
        short8 a2 = *(const short8*)(ap + k0 + 16);
        short8 a3 = *(const short8*)(ap + k0 + 24);
        short8 b0 = *(const short8*)(bp + k0);
        short8 b1 = *(const short8*)(bp + k0 + 8);
        short8 b2 = *(const short8*)(bp + k0 + 16);
        short8 b3 = *(const short8*)(bp + k0 + 24);
        *(short8*)(asd) = a0; *(short8*)(asd + 8) = a1;
        *(short8*)(asd + 16) = a2; *(short8*)(asd + 24) = a3;
        *(short8*)(bsd) = b0; *(short8*)(bsd + 8) = b1;
        *(short8*)(bsd + 16) = b2; *(short8*)(bsd + 24) = b3;
        __syncthreads();
        #pragma unroll
        for (int kk = 0; kk < 64; kk += 32) {
            short8 af[4], bf[4];
            #pragma unroll
            for (int t = 0; t < 4; ++t)
                af[t] = *(const short8*)&As[(wm + t * 16 + lo) * 72 + kk + qd * 8];
            #pragma unroll
            for (int t = 0; t < 4; ++t)
                bf[t] = *(const short8*)&Bs[(wn + t * 16 + lo) * 72 + kk + qd * 8];
            #pragma unroll
            for (int i = 0; i < 4; ++i)
                #pragma unroll
                for (int j = 0; j < 4; ++j)
                    acc[i][j] = __builtin_amdgcn_mfma_f32_16x16x32_bf16(
                        af[i], bf[j], acc[i][j], 0, 0, 0);
        }
        __syncthreads();
    }

    #pragma unroll
    for (int i = 0; i < 4; ++i) {
        int growb = m0 + wm + i * 16 + qd * 4;
        #pragma unroll
        for (int j = 0; j < 4; ++j) {
            int gc = n0 + wn + j * 16 + lo;
            #pragma unroll
            for (int r = 0; r < 4; ++r) {
                float v = acc[i][j][r];
                int grow = growb + r;
                if (OUTBF16) {
                    unsigned b = f2bf(v);
                    unsigned other = (unsigned)__shfl_xor((int)b, 1) & 0xffffu;
                    if ((lo & 1) == 0) {
                        unsigned pk = b | (other << 16);
                        *(unsigned*)((unsigned short*)Cout + (size_t)grow * N + gc) = pk;
                    }
                } else {
                    ((float*)Cout)[(size_t)grow * N + gc] = v;
                }
            }
        }
    }
}

// ---------------- MFMA attention: one (b,x,h) per block, 4 waves ----------
__global__ __launch_bounds__(256)
void attn_mfma(const unsigned short* __restrict__ qkv, const int* __restrict__ mask,
               unsigned short* __restrict__ attn_out) {
    __shared__ __align__(16) unsigned short Qs[128 * 40];
    __shared__ __align__(16) unsigned short Ks[128 * 40];
    __shared__ __align__(16) unsigned short Vt[32 * 136];
    __shared__ __align__(16) unsigned short Ps[128 * 136];
    __shared__ float invS[128];
    __shared__ float MselS[128];

    int blk = blockIdx.x;
    int h = blk & 7, bx = blk >> 3;
    int x = bx & 127;
    int tid = threadIdx.x;
    int wave = tid >> 6, lane = tid & 63, qd = lane >> 4, lo = lane & 15;

    // ---- staging: thread -> (row, half); 16 bf16 of each of q,k,v
    {
        int row = tid >> 1, half = tid & 1;
        const unsigned short* qp =
            qkv + (size_t)bx * SEQ * NQKV + row * NQKV + h * 32 + half * 16;
        short8 q0 = *(const short8*)qp;
        short8 q1 = *(const short8*)(qp + 8);
        short8 k0 = *(const short8*)(qp + 256);
        short8 k1 = *(const short8*)(qp + 264);
        short8 v0 = *(const short8*)(qp + 512);
        short8 v1 = *(const short8*)(qp + 520);

        if (h == 0) {  // rotary hits only cols 0..31 of q and k = head 0
            float t = half ? (-1.0f + (2.0f / 127.0f) * (float)row)
                           : (-1.0f + (2.0f / 127.0f) * (float)x);
            float qe[16], ke[16];
            #pragma unroll
            for (int j = 0; j < 8; ++j) {
                qe[j] = bf2f((unsigned short)q0[j]);
                qe[8 + j] = bf2f((unsigned short)q1[j]);
                ke[j] = bf2f((unsigned short)k0[j]);
                ke[8 + j] = bf2f((unsigned short)k1[j]);
            }
            #pragma unroll
            for (int p = 0; p < 8; ++p) {
                float th = t * INVF[p];
                float sn, cs;
                __sincosf(th, &sn, &cs);
                float a = qe[2 * p], b = qe[2 * p + 1];
                qe[2 * p] = a * cs - b * sn;
                qe[2 * p + 1] = b * cs + a * sn;
                float c = ke[2 * p], d = ke[2 * p + 1];
                ke[2 * p] = c * cs - d * sn;
                ke[2 * p + 1] = d * cs + c * sn;
            }
            #pragma unroll
            for (int j = 0; j < 8; ++j) {
                q0[j] = (short)f2bf(qe[j]);
                q1[j] = (short)f2bf(qe[8 + j]);
                k0[j] = (short)f2bf(ke[j]);
                k1[j] = (short)f2bf(ke[8 + j]);
            }
        }
        unsigned short* qs = &Qs[row * 40 + half * 16];
        *(short8*)qs = q0; *(short8*)(qs + 8) = q1;
        unsigned short* ks = &Ks[row * 40 + half * 16];
        *(short8*)ks = k0; *(short8*)(ks + 8) = k1;
        #pragma unroll
        for (int j = 0; j < 8; ++j) {
            Vt[(half * 16 + j) * 136 + row] = (unsigned short)v0[j];
            Vt[(half * 16 + 8 + j) * 136 + row] = (unsigned short)v1[j];
        }
    }
    if (tid < SEQ) MselS[tid] = mask[bx * SEQ + tid] ? 0.0f : 1.0f;
    __syncthreads();

    int m0 = wave * 32;

    // ---- S = Q K^T (strip of 32 q-rows per wave), masked exp
    short8 aq[2];
    #pragma unroll
    for (int t = 0; t < 2; ++t)
        aq[t] = *(const short8*)&Qs[(m0 + t * 16 + lo) * 40 + qd * 8];

    float ef[2][8][4];
    float msel[8];
    #pragma unroll
    for (int nt = 0; nt < 8; ++nt) msel[nt] = MselS[nt * 16 + lo];
    #pragma unroll
    for (int nt = 0; nt < 8; ++nt) {
        short8 bk = *(const short8*)&Ks[(nt * 16 + lo) * 40 + qd * 8];
        #pragma unroll
        for (int t = 0; t < 2; ++t) {
            floatx4 c = (floatx4){0.f, 0.f, 0.f, 0.f};
            c = __builtin_amdgcn_mfma_f32_16x16x32_bf16(aq[t], bk, c, 0, 0, 0);
            #pragma unroll
            for (int r = 0; r < 4; ++r)
                ef[t][nt][r] = __expf(c[r] * ATT_SCALE) * msel[nt];
        }
    }

    // ---- row sums -> invS; P -> LDS (A-layout row-major, bf16)
    #pragma unroll
    for (int t = 0; t < 2; ++t)
        #pragma unroll
        for (int r = 0; r < 4; ++r) {
            float s = 0.f;
            #pragma unroll
            for (int nt = 0; nt < 8; ++nt) s += ef[t][nt][r];
            s += __shfl_xor(s, 1);
            s += __shfl_xor(s, 2);
            s += __shfl_xor(s, 4);
            s += __shfl_xor(s, 8);
            if (lo == 0) invS[m0 + t * 16 + qd * 4 + r] = 1.0f / s;
        }
    #pragma unroll
    for (int t = 0; t < 2; ++t)
        #pragma unroll
        for (int nt = 0; nt < 8; ++nt)
            #pragma unroll
            for (int r = 0; r < 4; ++r)
                Ps[(m0 + t * 16 + qd * 4 + r) * 136 + nt * 16 + lo] =
                    f2bf(ef[t][nt][r]);
    // each wave reads back only its own rows -> no barrier needed

    // ---- O = P V
    floatx4 o[2][2];
    #pragma unroll
    for (int t = 0; t < 2; ++t)
        #pragma unroll
        for (int n = 0; n < 2; ++n) o[t][n] = (floatx4){0.f, 0.f, 0.f, 0.f};
    #pragma unroll
    for (int k0 = 0; k0 < 4; ++k0) {
        short8 pa[2], vb[2];
        #pragma unroll
        for (int t = 0; t < 2; ++t)
            pa[t] = *(const short8*)&Ps[(m0 + t * 16 + lo) * 136 + k0 * 32 + qd * 8];
        #pragma unroll
        for (int n = 0; n < 2; ++n)
            vb[n] = *(const short8*)&Vt[(n * 16 + lo) * 136 + k0 * 32 + qd * 8];
        #pragma unroll
        for (int t = 0; t < 2; ++t)
            #pragma unroll
            for (int n = 0; n < 2; ++n)
                o[t][n] = __builtin_amdgcn_mfma_f32_16x16x32_bf16(
                    pa[t], vb[n], o[t][n], 0, 0, 0);
    }

    // ---- normalize + store bf16 (pack 2 cols via shfl)
    #pragma unroll
    for (int t = 0; t < 2; ++t)
        #pragma unroll
        for (int r = 0; r < 4; ++r) {
            int qrow = m0 + t * 16 + qd * 4 + r;
            float inv = invS[qrow];
            #pragma unroll
            for (int n = 0; n < 2; ++n) {
                float v = o[t][n][r] * inv;
                unsigned b = f2bf(v);
                unsigned other = (unsigned)__shfl_xor((int)b, 1) & 0xffffu;
                if ((lo & 1) == 0) {
                    unsigned pk = b | (other << 16);
                    *(unsigned*)&attn_out[((size_t)bx * SEQ + qrow) * DM +
                                          h * 32 + n * 16 + lo] = pk;
                }
            }
        }
}

extern "C" void kernel_launch(void* const* d_in, const int* in_sizes, int n_in,
                              void* d_out, int out_size, void* d_ws, size_t ws_size,
                              hipStream_t stream) {
    const float* pair_act = (const float*)d_in[0];
    const int* pair_mask = (const int*)d_in[1];
    const float* ln_gamma = (const float*)d_in[2];
    const float* ln_beta = (const float*)d_in[3];
    const float* Wqkv = (const float*)d_in[4];
    const float* Wout = (const float*)d_in[5];
    float* out = (float*)d_out;

    char* ws = (char*)d_ws;
    unsigned short* qkv_bf = (unsigned short*)ws;                   // 50,331,648 B
    unsigned short* xln_bf = (unsigned short*)(ws + 50331648);      // 16,777,216 B
    unsigned short* attn_bf = (unsigned short*)(ws + 67108864);     // 16,777,216 B
    unsigned short* wqkv_bf = (unsigned short*)(ws + 83886080);     //    393,216 B
    unsigned short* wout_bf = (unsigned short*)(ws + 84279296);     //    131,072 B

    const int R = 2 * SEQ * SEQ;  // 32768 rows

    convw<<<768, 256, 0, stream>>>(Wqkv, Wout, wqkv_bf, wout_bf);
    ln_kernel<<<R, 256, 0, stream>>>(pair_act, ln_gamma, ln_beta, xln_bf);
    gemm_mfma<true><<<dim3(R / 128, NQKV / 128), 256, 0, stream>>>(
        xln_bf, wqkv_bf, qkv_bf, NQKV);
    attn_mfma<<<2 * SEQ * 8, 256, 0, stream>>>(qkv_bf, pair_mask, attn_bf);
    gemm_mfma<false><<<dim3(R / 128, DM / 128), 256, 0, stream>>>(
        attn_bf, wout_bf, out, DM);
}

// Round 3
// 157.340 us; speedup vs baseline: 2.7713x; 1.1391x over previous
//
#include <hip/hip_runtime.h>
#include <math.h>

typedef __attribute__((ext_vector_type(8))) short short8;
typedef __attribute__((ext_vector_type(4))) short short4v;
typedef __attribute__((ext_vector_type(4))) float floatx4;

#define SEQ 128
#define DM 256
#define NQKV 768
#define LN_EPS 1e-5f
#define ATT_SCALE 0.17677669529663687f  // 32^-0.5

__device__ __constant__ float INVF[8] = {
    1.0f, 0.31622776601683794f, 0.1f, 0.031622776601683794f,
    0.01f, 0.0031622776601683794f, 0.001f, 0.00031622776601683794f};

__device__ inline unsigned short f2bf(float f) {
    unsigned u = __float_as_uint(f);
    u += 0x7fffu + ((u >> 16) & 1u);
    return (unsigned short)(u >> 16);
}

// ---------- prep: LN (wave-per-row, 4 rows/block) + weight conversion ------
// grid: [0,8192) -> LN rows; [8192, 8960) -> weight rows.
__global__ __launch_bounds__(256)
void prep_kernel(const float* __restrict__ pa, const float* __restrict__ gamma,
                 const float* __restrict__ beta, unsigned short* __restrict__ xln,
                 const float* __restrict__ wq, const float* __restrict__ wo,
                 unsigned short* __restrict__ bq, unsigned short* __restrict__ bo) {
    int bid = blockIdx.x;
    int tid = threadIdx.x;
    if (bid < 8192) {
        int lane = tid & 63, wid = tid >> 6;
        int row = bid * 4 + wid;
        float4 v = *(const float4*)(pa + (size_t)row * DM + lane * 4);
        float s = v.x + v.y + v.z + v.w;
        #pragma unroll
        for (int o = 32; o > 0; o >>= 1) s += __shfl_xor(s, o);
        float mean = s * (1.0f / DM);
        float d0 = v.x - mean, d1 = v.y - mean, d2 = v.z - mean, d3 = v.w - mean;
        float sq = d0 * d0 + d1 * d1 + d2 * d2 + d3 * d3;
        #pragma unroll
        for (int o = 32; o > 0; o >>= 1) sq += __shfl_xor(sq, o);
        float r = rsqrtf(sq * (1.0f / DM) + LN_EPS);
        float4 g = *(const float4*)(gamma + lane * 4);
        float4 b = *(const float4*)(beta + lane * 4);
        short4v o4;
        o4[0] = (short)f2bf(d0 * r * g.x + b.x);
        o4[1] = (short)f2bf(d1 * r * g.y + b.y);
        o4[2] = (short)f2bf(d2 * r * g.z + b.z);
        o4[3] = (short)f2bf(d3 * r * g.w + b.w);
        *(short4v*)(xln + (size_t)row * DM + lane * 4) = o4;
    } else {
        int e = bid - 8192;
        bq[e * DM + tid] = f2bf(wq[e * DM + tid]);
        if (e < DM) bo[e * DM + tid] = f2bf(wo[e * DM + tid]);
    }
}

// ---------------- MFMA GEMM: C[M,N] = A[M,256] * B[N,256]^T ----------------
// 128x128 tile, BK=64, 4 waves each 64x64. Optional rotary epilogue (qkv).
template <bool OUTBF16, bool ROT>
__global__ __launch_bounds__(256)
void gemm_mfma(const unsigned short* __restrict__ A,
               const unsigned short* __restrict__ B,
               void* __restrict__ Cout, int N) {
    __shared__ __align__(16) unsigned short As[128 * 72];
    __shared__ __align__(16) unsigned short Bs[128 * 72];
    int m0 = blockIdx.x * 128, n0 = blockIdx.y * 128;
    int tid = threadIdx.x;
    int wave = tid >> 6, lane = tid & 63, qd = lane >> 4, lo = lane & 15;
    int wm = (wave & 1) * 64, wn = (wave >> 1) * 64;

    floatx4 acc[4][4];
    #pragma unroll
    for (int i = 0; i < 4; ++i)
        #pragma unroll
        for (int j = 0; j < 4; ++j) acc[i][j] = (floatx4){0.f, 0.f, 0.f, 0.f};

    int srow = tid >> 1, shalf = tid & 1;
    const unsigned short* ap = A + (size_t)(m0 + srow) * 256 + shalf * 32;
    const unsigned short* bp = B + (size_t)(n0 + srow) * 256 + shalf * 32;
    unsigned short* asd = &As[srow * 72 + shalf * 32];
    unsigned short* bsd = &Bs[srow * 72 + shalf * 32];

    for (int k0 = 0; k0 < 256; k0 += 64) {
        short8 a0 = *(const short8*)(ap + k0);
        short8 a1 = *(const short8*)(ap + k0 + 8);
        short8 a2 = *(const short8*)(ap + k0 + 16);
        short8 a3 = *(const short8*)(ap + k0 + 24);
        short8 b0 = *(const short8*)(bp + k0);
        short8 b1 = *(const short8*)(bp + k0 + 8);
        short8 b2 = *(const short8*)(bp + k0 + 16);
        short8 b3 = *(const short8*)(bp + k0 + 24);
        *(short8*)(asd) = a0; *(short8*)(asd + 8) = a1;
        *(short8*)(asd + 16) = a2; *(short8*)(asd + 24) = a3;
        *(short8*)(bsd) = b0; *(short8*)(bsd + 8) = b1;
        *(short8*)(bsd + 16) = b2; *(short8*)(bsd + 24) = b3;
        __syncthreads();
        #pragma unroll
        for (int kk = 0; kk < 64; kk += 32) {
            short8 af[4], bf[4];
            #pragma unroll
            for (int t = 0; t < 4; ++t)
                af[t] = *(const short8*)&As[(wm + t * 16 + lo) * 72 + kk + qd * 8];
            #pragma unroll
            for (int t = 0; t < 4; ++t)
                bf[t] = *(const short8*)&Bs[(wn + t * 16 + lo) * 72 + kk + qd * 8];
            #pragma unroll
            for (int i = 0; i < 4; ++i)
                #pragma unroll
                for (int j = 0; j < 4; ++j)
                    acc[i][j] = __builtin_amdgcn_mfma_f32_16x16x32_bf16(
                        af[i], bf[j], acc[i][j], 0, 0, 0);
        }
        __syncthreads();
    }

    if (ROT) {
        // rotary applies to global cols 0..31 (q head 0) and 256..287 (k head 0)
        #pragma unroll
        for (int j = 0; j < 4; ++j) {
            int gcb = n0 + wn + j * 16;
            int sect = gcb >> 5;
            if (sect == 0 || sect == 8) {
                int p = (((j & 1) * 16) + lo) >> 1;  // pair index 0..15
                float invf = INVF[p & 7];
                float sgn = (lo & 1) ? 1.0f : -1.0f;
                #pragma unroll
                for (int i = 0; i < 4; ++i) {
                    #pragma unroll
                    for (int r = 0; r < 4; ++r) {
                        int grow = m0 + wm + i * 16 + qd * 4 + r;
                        int yy = grow & 127, xx = (grow >> 7) & 127;
                        float tpos = (p < 8) ? (-1.0f + (2.0f / 127.0f) * (float)xx)
                                             : (-1.0f + (2.0f / 127.0f) * (float)yy);
                        float th = tpos * invf;
                        float sn, cs;
                        __sincosf(th, &sn, &cs);
                        float v = acc[i][j][r];
                        float pv = __shfl_xor(v, 1);
                        acc[i][j][r] = v * cs + sgn * pv * sn;
                    }
                }
            }
        }
    }

    #pragma unroll
    for (int i = 0; i < 4; ++i) {
        int growb = m0 + wm + i * 16 + qd * 4;
        #pragma unroll
        for (int j = 0; j < 4; ++j) {
            int gc = n0 + wn + j * 16 + lo;
            #pragma unroll
            for (int r = 0; r < 4; ++r) {
                float v = acc[i][j][r];
                int grow = growb + r;
                if (OUTBF16) {
                    unsigned b = f2bf(v);
                    unsigned other = (unsigned)__shfl_xor((int)b, 1) & 0xffffu;
                    if ((lo & 1) == 0) {
                        unsigned pk = b | (other << 16);
                        *(unsigned*)((unsigned short*)Cout + (size_t)grow * N + gc) = pk;
                    }
                } else {
                    ((float*)Cout)[(size_t)grow * N + gc] = v;
                }
            }
        }
    }
}

// ---------------- MFMA attention v2: Q/K frags direct from global ----------
__global__ __launch_bounds__(256)
void attn_mfma(const unsigned short* __restrict__ qkv, const int* __restrict__ mask,
               unsigned short* __restrict__ attn_out) {
    __shared__ __align__(16) unsigned short Vt[32 * 136];
    __shared__ __align__(16) unsigned short Ps[128 * 136];

    int blk = blockIdx.x;
    int h = blk & 7, bx = blk >> 3;
    int tid = threadIdx.x;
    int wave = tid >> 6, lane = tid & 63, qd = lane >> 4, lo = lane & 15;
    const unsigned short* base = qkv + (size_t)bx * SEQ * NQKV;

    // ---- stage V transposed (only V needs LDS; Q/K frag layouts are
    // 16B-contiguous per lane and load straight from global)
    {
        int row = tid >> 1, half = tid & 1;
        const unsigned short* vp = base + row * NQKV + 512 + h * 32 + half * 16;
        short8 v0 = *(const short8*)vp;
        short8 v1 = *(const short8*)(vp + 8);
        #pragma unroll
        for (int j = 0; j < 8; ++j) {
            Vt[(half * 16 + j) * 136 + row] = (unsigned short)v0[j];
            Vt[(half * 16 + 8 + j) * 136 + row] = (unsigned short)v1[j];
        }
    }
    __syncthreads();

    int m0 = wave * 32;

    // ---- Q fragments (A-layout: row=lo, k=qd*8+j -> contiguous in qkv)
    short8 aq[2];
    #pragma unroll
    for (int t = 0; t < 2; ++t)
        aq[t] = *(const short8*)(base + (m0 + t * 16 + lo) * NQKV + h * 32 + qd * 8);

    float msel[8];
    #pragma unroll
    for (int nt = 0; nt < 8; ++nt)
        msel[nt] = mask[bx * SEQ + nt * 16 + lo] ? 0.0f : 1.0f;

    // ---- S = Q K^T, masked exp; stream row-sums + Ps stores per nt
    float s[2][4] = {};
    #pragma unroll
    for (int nt = 0; nt < 8; ++nt) {
        short8 bk = *(const short8*)(base + (nt * 16 + lo) * NQKV + 256 + h * 32 + qd * 8);
        #pragma unroll
        for (int t = 0; t < 2; ++t) {
            floatx4 c = (floatx4){0.f, 0.f, 0.f, 0.f};
            c = __builtin_amdgcn_mfma_f32_16x16x32_bf16(aq[t], bk, c, 0, 0, 0);
            #pragma unroll
            for (int r = 0; r < 4; ++r) {
                float e = __expf(c[r] * ATT_SCALE) * msel[nt];
                s[t][r] += e;
                Ps[(m0 + t * 16 + qd * 4 + r) * 136 + nt * 16 + lo] = f2bf(e);
            }
        }
    }

    // ---- row-sum across lo lanes -> inv (all lanes, no LDS)
    float inv[2][4];
    #pragma unroll
    for (int t = 0; t < 2; ++t)
        #pragma unroll
        for (int r = 0; r < 4; ++r) {
            float v = s[t][r];
            v += __shfl_xor(v, 1);
            v += __shfl_xor(v, 2);
            v += __shfl_xor(v, 4);
            v += __shfl_xor(v, 8);
            inv[t][r] = 1.0f / v;
        }

    // ---- O = P V (Ps is wave-private -> no barrier)
    floatx4 o[2][2];
    #pragma unroll
    for (int t = 0; t < 2; ++t)
        #pragma unroll
        for (int n = 0; n < 2; ++n) o[t][n] = (floatx4){0.f, 0.f, 0.f, 0.f};
    #pragma unroll
    for (int k0 = 0; k0 < 4; ++k0) {
        short8 pa[2], vb[2];
        #pragma unroll
        for (int t = 0; t < 2; ++t)
            pa[t] = *(const short8*)&Ps[(m0 + t * 16 + lo) * 136 + k0 * 32 + qd * 8];
        #pragma unroll
        for (int n = 0; n < 2; ++n)
            vb[n] = *(const short8*)&Vt[(n * 16 + lo) * 136 + k0 * 32 + qd * 8];
        #pragma unroll
        for (int t = 0; t < 2; ++t)
            #pragma unroll
            for (int n = 0; n < 2; ++n)
                o[t][n] = __builtin_amdgcn_mfma_f32_16x16x32_bf16(
                    pa[t], vb[n], o[t][n], 0, 0, 0);
    }

    // ---- normalize + store bf16 (pack 2 cols via shfl)
    #pragma unroll
    for (int t = 0; t < 2; ++t)
        #pragma unroll
        for (int r = 0; r < 4; ++r) {
            int qrow = m0 + t * 16 + qd * 4 + r;
            float iv = inv[t][r];
            #pragma unroll
            for (int n = 0; n < 2; ++n) {
                float v = o[t][n][r] * iv;
                unsigned b = f2bf(v);
                unsigned other = (unsigned)__shfl_xor((int)b, 1) & 0xffffu;
                if ((lo & 1) == 0) {
                    unsigned pk = b | (other << 16);
                    *(unsigned*)&attn_out[((size_t)bx * SEQ + qrow) * DM +
                                          h * 32 + n * 16 + lo] = pk;
                }
            }
        }
}

extern "C" void kernel_launch(void* const* d_in, const int* in_sizes, int n_in,
                              void* d_out, int out_size, void* d_ws, size_t ws_size,
                              hipStream_t stream) {
    const float* pair_act = (const float*)d_in[0];
    const int* pair_mask = (const int*)d_in[1];
    const float* ln_gamma = (const float*)d_in[2];
    const float* ln_beta = (const float*)d_in[3];
    const float* Wqkv = (const float*)d_in[4];
    const float* Wout = (const float*)d_in[5];
    float* out = (float*)d_out;

    char* ws = (char*)d_ws;
    unsigned short* qkv_bf = (unsigned short*)ws;                   // 50,331,648 B
    unsigned short* xln_bf = (unsigned short*)(ws + 50331648);      // 16,777,216 B
    unsigned short* attn_bf = (unsigned short*)(ws + 67108864);     // 16,777,216 B
    unsigned short* wqkv_bf = (unsigned short*)(ws + 83886080);     //    393,216 B
    unsigned short* wout_bf = (unsigned short*)(ws + 84279296);     //    131,072 B

    const int R = 2 * SEQ * SEQ;  // 32768 rows

    prep_kernel<<<8960, 256, 0, stream>>>(pair_act, ln_gamma, ln_beta, xln_bf,
                                          Wqkv, Wout, wqkv_bf, wout_bf);
    gemm_mfma<true, true><<<dim3(R / 128, NQKV / 128), 256, 0, stream>>>(
        xln_bf, wqkv_bf, qkv_bf, NQKV);
    attn_mfma<<<2 * SEQ * 8, 256, 0, stream>>>(qkv_bf, pair_mask, attn_bf);
    gemm_mfma<false, false><<<dim3(R / 128, DM / 128), 256, 0, stream>>>(
        attn_bf, wout_bf, out, DM);
}

// Round 4
// 151.037 us; speedup vs baseline: 2.8870x; 1.0417x over previous
//
#include <hip/hip_runtime.h>
#include <math.h>
#include <stdint.h>

typedef __attribute__((ext_vector_type(8))) short short8;
typedef __attribute__((ext_vector_type(4))) short short4v;
typedef __attribute__((ext_vector_type(4))) float floatx4;

#define SEQ 128
#define DM 256
#define NQKV 768
#define LN_EPS 1e-5f
#define ATT_SCALE 0.17677669529663687f  // 32^-0.5

__device__ __constant__ float INVF[8] = {
    1.0f, 0.31622776601683794f, 0.1f, 0.031622776601683794f,
    0.01f, 0.0031622776601683794f, 0.001f, 0.00031622776601683794f};

__device__ inline unsigned short f2bf(float f) {
    unsigned u = __float_as_uint(f);
    u += 0x7fffu + ((u >> 16) & 1u);
    return (unsigned short)(u >> 16);
}

// async global->LDS, 16B per lane. Generic->AS cast via integer round-trip:
// AS3 ptr = low 32 bits of generic LDS addr (aperture low half is the offset).
__device__ inline void gl_lds16(const unsigned short* g, unsigned short* l) {
    __builtin_amdgcn_global_load_lds(
        (const __attribute__((address_space(1))) void*)(uintptr_t)g,
        (__attribute__((address_space(3))) void*)(uintptr_t)l, 16, 0, 0);
}

// ---------- prep: LN (wave-per-row, 4 rows/block) + weight conversion ------
__global__ __launch_bounds__(256)
void prep_kernel(const float* __restrict__ pa, const float* __restrict__ gamma,
                 const float* __restrict__ beta, unsigned short* __restrict__ xln,
                 const float* __restrict__ wq, const float* __restrict__ wo,
                 unsigned short* __restrict__ bq, unsigned short* __restrict__ bo) {
    int bid = blockIdx.x;
    int tid = threadIdx.x;
    if (bid < 8192) {
        int lane = tid & 63, wid = tid >> 6;
        int row = bid * 4 + wid;
        float4 v = *(const float4*)(pa + (size_t)row * DM + lane * 4);
        float s = v.x + v.y + v.z + v.w;
        #pragma unroll
        for (int o = 32; o > 0; o >>= 1) s += __shfl_xor(s, o);
        float mean = s * (1.0f / DM);
        float d0 = v.x - mean, d1 = v.y - mean, d2 = v.z - mean, d3 = v.w - mean;
        float sq = d0 * d0 + d1 * d1 + d2 * d2 + d3 * d3;
        #pragma unroll
        for (int o = 32; o > 0; o >>= 1) sq += __shfl_xor(sq, o);
        float r = rsqrtf(sq * (1.0f / DM) + LN_EPS);
        float4 g = *(const float4*)(gamma + lane * 4);
        float4 b = *(const float4*)(beta + lane * 4);
        short4v o4;
        o4[0] = (short)f2bf(d0 * r * g.x + b.x);
        o4[1] = (short)f2bf(d1 * r * g.y + b.y);
        o4[2] = (short)f2bf(d2 * r * g.z + b.z);
        o4[3] = (short)f2bf(d3 * r * g.w + b.w);
        *(short4v*)(xln + (size_t)row * DM + lane * 4) = o4;
    } else {
        int e = bid - 8192;
        bq[e * DM + tid] = f2bf(wq[e * DM + tid]);
        if (e < DM) bo[e * DM + tid] = f2bf(wo[e * DM + tid]);
    }
}

// ---------------- MFMA GEMM: C[M,N] = A[M,256] * B[N,256]^T ----------------
// 128x128 tile, BK=64, 4 waves each 64x64. Async global_load_lds staging
// with XOR-swizzled LDS (chunk col ^= row&7): DMA-compatible (no padding),
// conflict-free fragment reads (2-way aliasing only).
template <bool OUTBF16, bool ROT>
__global__ __launch_bounds__(256)
void gemm_mfma(const unsigned short* __restrict__ A,
               const unsigned short* __restrict__ B,
               void* __restrict__ Cout, int N) {
    __shared__ __align__(16) unsigned short As[128 * 64];
    __shared__ __align__(16) unsigned short Bs[128 * 64];
    int m0 = blockIdx.x * 128, n0 = blockIdx.y * 128;
    int tid = threadIdx.x;
    int wave = tid >> 6, lane = tid & 63, qd = lane >> 4, lo = lane & 15;
    int wm = (wave & 1) * 64, wn = (wave >> 1) * 64;

    floatx4 acc[4][4];
    #pragma unroll
    for (int i = 0; i < 4; ++i)
        #pragma unroll
        for (int j = 0; j < 4; ++j) acc[i][j] = (floatx4){0.f, 0.f, 0.f, 0.f};

    // staging decode: chunk = rbase*8 + lane; stored slot sc = lane&7;
    // global chunk col c = sc ^ (row&7), row = rbase + (lane>>3)
    int rsub = lane >> 3;
    int csub = (lane & 7) ^ rsub;

    for (int k0 = 0; k0 < 256; k0 += 64) {
        #pragma unroll
        for (int t = 0; t < 4; ++t) {
            int rbase = (wave * 4 + t) * 8;
            int row = rbase + rsub;
            gl_lds16(A + (size_t)(m0 + row) * 256 + k0 + csub * 8, &As[rbase * 64]);
            gl_lds16(B + (size_t)(n0 + row) * 256 + k0 + csub * 8, &Bs[rbase * 64]);
        }
        __syncthreads();
        #pragma unroll
        for (int kk = 0; kk < 64; kk += 32) {
            int kkc = kk >> 3;  // chunk col base (0 or 4)
            short8 af[4], bf[4];
            #pragma unroll
            for (int t = 0; t < 4; ++t) {
                int row = wm + t * 16 + lo;
                int sc = (kkc + qd) ^ (row & 7);
                af[t] = *(const short8*)&As[row * 64 + sc * 8];
            }
            #pragma unroll
            for (int t = 0; t < 4; ++t) {
                int row = wn + t * 16 + lo;
                int sc = (kkc + qd) ^ (row & 7);
                bf[t] = *(const short8*)&Bs[row * 64 + sc * 8];
            }
            #pragma unroll
            for (int i = 0; i < 4; ++i)
                #pragma unroll
                for (int j = 0; j < 4; ++j)
                    acc[i][j] = __builtin_amdgcn_mfma_f32_16x16x32_bf16(
                        af[i], bf[j], acc[i][j], 0, 0, 0);
        }
        __syncthreads();
    }

    if (ROT) {
        // rotary applies to global cols 0..31 (q head 0) and 256..287 (k head 0)
        #pragma unroll
        for (int j = 0; j < 4; ++j) {
            int gcb = n0 + wn + j * 16;
            int sect = gcb >> 5;
            if (sect == 0 || sect == 8) {
                int p = (((j & 1) * 16) + lo) >> 1;  // pair index 0..15
                float invf = INVF[p & 7];
                float sgn = (lo & 1) ? 1.0f : -1.0f;
                #pragma unroll
                for (int i = 0; i < 4; ++i) {
                    #pragma unroll
                    for (int r = 0; r < 4; ++r) {
                        int grow = m0 + wm + i * 16 + qd * 4 + r;
                        int yy = grow & 127, xx = (grow >> 7) & 127;
                        float tpos = (p < 8) ? (-1.0f + (2.0f / 127.0f) * (float)xx)
                                             : (-1.0f + (2.0f / 127.0f) * (float)yy);
                        float th = tpos * invf;
                        float sn, cs;
                        __sincosf(th, &sn, &cs);
                        float v = acc[i][j][r];
                        float pv = __shfl_xor(v, 1);
                        acc[i][j][r] = v * cs + sgn * pv * sn;
                    }
                }
            }
        }
    }

    #pragma unroll
    for (int i = 0; i < 4; ++i) {
        int growb = m0 + wm + i * 16 + qd * 4;
        #pragma unroll
        for (int j = 0; j < 4; ++j) {
            int gc = n0 + wn + j * 16 + lo;
            #pragma unroll
            for (int r = 0; r < 4; ++r) {
                float v = acc[i][j][r];
                int grow = growb + r;
                if (OUTBF16) {
                    unsigned b = f2bf(v);
                    unsigned other = (unsigned)__shfl_xor((int)b, 1) & 0xffffu;
                    if ((lo & 1) == 0) {
                        unsigned pk = b | (other << 16);
                        *(unsigned*)((unsigned short*)Cout + (size_t)grow * N + gc) = pk;
                    }
                } else {
                    ((float*)Cout)[(size_t)grow * N + gc] = v;
                }
            }
        }
    }
}

// ---------------- MFMA attention: Q/K frags direct from global ------------
__global__ __launch_bounds__(256)
void attn_mfma(const unsigned short* __restrict__ qkv, const int* __restrict__ mask,
               unsigned short* __restrict__ attn_out) {
    __shared__ __align__(16) unsigned short Vt[32 * 136];
    __shared__ __align__(16) unsigned short Ps[128 * 136];

    int blk = blockIdx.x;
    int h = blk & 7, bx = blk >> 3;
    int tid = threadIdx.x;
    int wave = tid >> 6, lane = tid & 63, qd = lane >> 4, lo = lane & 15;
    const unsigned short* base = qkv + (size_t)bx * SEQ * NQKV;

    // ---- stage V transposed
    {
        int row = tid >> 1, half = tid & 1;
        const unsigned short* vp = base + row * NQKV + 512 + h * 32 + half * 16;
        short8 v0 = *(const short8*)vp;
        short8 v1 = *(const short8*)(vp + 8);
        #pragma unroll
        for (int j = 0; j < 8; ++j) {
            Vt[(half * 16 + j) * 136 + row] = (unsigned short)v0[j];
            Vt[(half * 16 + 8 + j) * 136 + row] = (unsigned short)v1[j];
        }
    }
    __syncthreads();

    int m0 = wave * 32;

    short8 aq[2];
    #pragma unroll
    for (int t = 0; t < 2; ++t)
        aq[t] = *(const short8*)(base + (m0 + t * 16 + lo) * NQKV + h * 32 + qd * 8);

    float msel[8];
    #pragma unroll
    for (int nt = 0; nt < 8; ++nt)
        msel[nt] = mask[bx * SEQ + nt * 16 + lo] ? 0.0f : 1.0f;

    float s[2][4] = {};
    #pragma unroll
    for (int nt = 0; nt < 8; ++nt) {
        short8 bk = *(const short8*)(base + (nt * 16 + lo) * NQKV + 256 + h * 32 + qd * 8);
        #pragma unroll
        for (int t = 0; t < 2; ++t) {
            floatx4 c = (floatx4){0.f, 0.f, 0.f, 0.f};
            c = __builtin_amdgcn_mfma_f32_16x16x32_bf16(aq[t], bk, c, 0, 0, 0);
            #pragma unroll
            for (int r = 0; r < 4; ++r) {
                float e = __expf(c[r] * ATT_SCALE) * msel[nt];
                s[t][r] += e;
                Ps[(m0 + t * 16 + qd * 4 + r) * 136 + nt * 16 + lo] = f2bf(e);
            }
        }
    }

    float inv[2][4];
    #pragma unroll
    for (int t = 0; t < 2; ++t)
        #pragma unroll
        for (int r = 0; r < 4; ++r) {
            float v = s[t][r];
            v += __shfl_xor(v, 1);
            v += __shfl_xor(v, 2);
            v += __shfl_xor(v, 4);
            v += __shfl_xor(v, 8);
            inv[t][r] = 1.0f / v;
        }

    floatx4 o[2][2];
    #pragma unroll
    for (int t = 0; t < 2; ++t)
        #pragma unroll
        for (int n = 0; n < 2; ++n) o[t][n] = (floatx4){0.f, 0.f, 0.f, 0.f};
    #pragma unroll
    for (int k0 = 0; k0 < 4; ++k0) {
        short8 pa[2], vb[2];
        #pragma unroll
        for (int t = 0; t < 2; ++t)
            pa[t] = *(const short8*)&Ps[(m0 + t * 16 + lo) * 136 + k0 * 32 + qd * 8];
        #pragma unroll
        for (int n = 0; n < 2; ++n)
            vb[n] = *(const short8*)&Vt[(n * 16 + lo) * 136 + k0 * 32 + qd * 8];
        #pragma unroll
        for (int t = 0; t < 2; ++t)
            #pragma unroll
            for (int n = 0; n < 2; ++n)
                o[t][n] = __builtin_amdgcn_mfma_f32_16x16x32_bf16(
                    pa[t], vb[n], o[t][n], 0, 0, 0);
    }

    #pragma unroll
    for (int t = 0; t < 2; ++t)
        #pragma unroll
        for (int r = 0; r < 4; ++r) {
            int qrow = m0 + t * 16 + qd * 4 + r;
            float iv = inv[t][r];
            #pragma unroll
            for (int n = 0; n < 2; ++n) {
                float v = o[t][n][r] * iv;
                unsigned b = f2bf(v);
                unsigned other = (unsigned)__shfl_xor((int)b, 1) & 0xffffu;
                if ((lo & 1) == 0) {
                    unsigned pk = b | (other << 16);
                    *(unsigned*)&attn_out[((size_t)bx * SEQ + qrow) * DM +
                                          h * 32 + n * 16 + lo] = pk;
                }
            }
        }
}

extern "C" void kernel_launch(void* const* d_in, const int* in_sizes, int n_in,
                              void* d_out, int out_size, void* d_ws, size_t ws_size,
                              hipStream_t stream) {
    const float* pair_act = (const float*)d_in[0];
    const int* pair_mask = (const int*)d_in[1];
    const float* ln_gamma = (const float*)d_in[2];
    const float* ln_beta = (const float*)d_in[3];
    const float* Wqkv = (const float*)d_in[4];
    const float* Wout = (const float*)d_in[5];
    float* out = (float*)d_out;

    char* ws = (char*)d_ws;
    unsigned short* qkv_bf = (unsigned short*)ws;                   // 50,331,648 B
    unsigned short* xln_bf = (unsigned short*)(ws + 50331648);      // 16,777,216 B
    unsigned short* attn_bf = (unsigned short*)(ws + 67108864);     // 16,777,216 B
    unsigned short* wqkv_bf = (unsigned short*)(ws + 83886080);     //    393,216 B
    unsigned short* wout_bf = (unsigned short*)(ws + 84279296);     //    131,072 B

    const int R = 2 * SEQ * SEQ;  // 32768 rows

    prep_kernel<<<8960, 256, 0, stream>>>(pair_act, ln_gamma, ln_beta, xln_bf,
                                          Wqkv, Wout, wqkv_bf, wout_bf);
    gemm_mfma<true, true><<<dim3(R / 128, NQKV / 128), 256, 0, stream>>>(
        xln_bf, wqkv_bf, qkv_bf, NQKV);
    attn_mfma<<<2 * SEQ * 8, 256, 0, stream>>>(qkv_bf, pair_mask, attn_bf);
    gemm_mfma<false, false><<<dim3(R / 128, DM / 128), 256, 0, stream>>>(
        attn_bf, wout_bf, out, DM);
}